// Round 1
// baseline (488.820 us; speedup 1.0000x reference)
//
#include <hip/hip_runtime.h>
#include <hip/hip_bf16.h>
#include <stdint.h>

#define NB 32
#define NC 512
#define NP 576
#define NN 4096

typedef __attribute__((ext_vector_type(8))) short short8;
typedef __attribute__((ext_vector_type(4))) float floatx4;

#define AS1 __attribute__((address_space(1)))
#define AS3 __attribute__((address_space(3)))

static __device__ __forceinline__ void gl_lds16(const void* g, void* l) {
  __builtin_amdgcn_global_load_lds((const AS1 uint32_t*)g, (AS3 uint32_t*)l, 16, 0, 0);
}

// ---------------- K1: inverse L2 norms over channel dim ----------------
__global__ void norms_kernel(const float* __restrict__ in, float* __restrict__ invn,
                             int nsp, int total) {
  int idx = blockIdx.x * 256 + threadIdx.x;
  if (idx >= total) return;
  int b = idx / nsp, sp = idx - b * nsp;
  const float* p = in + (size_t)b * NC * nsp + sp;
  float s = 0.f;
#pragma unroll 8
  for (int c = 0; c < NC; ++c) { float v = p[(size_t)c * nsp]; s = fmaf(v, v, s); }
  invn[idx] = 1.0f / fmaxf(sqrtf(s), 1e-12f);
}

// ---------------- K2: transpose [C][sp] -> [sp][C], scale, bf16 ----------------
__global__ void transpose_kernel(const float* __restrict__ in, const float* __restrict__ invn,
                                 __hip_bfloat16* __restrict__ out, int nsp) {
  __shared__ float tile[64][65];
  int b = blockIdx.z, c0 = blockIdx.y * 64, p0 = blockIdx.x * 64;
  int tx = threadIdx.x & 63, ty = threadIdx.x >> 6;
  const float* src = in + ((size_t)b * NC + c0) * nsp + p0;
#pragma unroll
  for (int r = ty; r < 64; r += 4) tile[r][tx] = src[(size_t)r * nsp + tx];
  __syncthreads();
  __hip_bfloat16* dst = out + ((size_t)b * nsp + p0) * NC + c0;
#pragma unroll
  for (int r = ty; r < 64; r += 4) {
    float iv = invn[b * nsp + p0 + r];
    dst[(size_t)r * NC + tx] = __float2bfloat16(tile[tx][r] * iv);
  }
}

// ---------------- K3: fused GEMM + softmax-reduction ----------------
#define BM 96
#define BN 128
#define BK 32
#define JCHUNK 1024
#define NJC 4
#define NJS 8            // JCHUNK / BN
#define NKT 16           // NC / BK
#define ABYTES (BM * BK * 2)              // 6144
#define SLICE (ABYTES + BN * BK * 2)      // 14336
#define NISSUE (SLICE / 1024)             // 14
#define NSTEP (NJS * NKT)                 // 128

__global__ void affinity_kernel(const __hip_bfloat16* __restrict__ srcT,
                                const __hip_bfloat16* __restrict__ dstT,
                                float* __restrict__ partials) {
  const int it = blockIdx.x, jc = blockIdx.y, b = blockIdx.z;
  const int i0 = it * BM;
  const int tid = threadIdx.x, lane = tid & 63, w = tid >> 6;
  const int wm = w & 1, wn = w >> 1;

  __shared__ __align__(16) char lds[2][SLICE];
  __shared__ float red[2 * BM * 3];

  // ---- staging descriptors (<=2 A-issues, <=2 B-issues per wave) ----
  int qA[2], qB[2];
  int nA = 0, nB = 0;
  for (int q = w; q < NISSUE; q += 4) {
    if (q < ABYTES / 1024) qA[nA++] = q; else qB[nB++] = q;
  }
  const char* gA[2]; uint32_t loA[2];
#pragma unroll
  for (int t2 = 0; t2 < 2; ++t2) {
    gA[t2] = nullptr; loA[t2] = 0;
    if (t2 < nA) {
      int q = qA[t2];
      uint32_t o = (uint32_t)q * 1024u + (uint32_t)lane * 16u;
      uint32_t row = o >> 6, colb = o & 63u;
      uint32_t csw = colb ^ ((row & 3u) << 4);
      gA[t2] = (const char*)srcT + ((size_t)(b * NP + i0 + (int)row)) * (NC * 2) + csw;
      loA[t2] = (uint32_t)q * 1024u;
    }
  }
  uint32_t rowpartB[2]; uint32_t loB[2];
#pragma unroll
  for (int t2 = 0; t2 < 2; ++t2) {
    rowpartB[t2] = 0; loB[t2] = 0;
    if (t2 < nB) {
      int q = qB[t2] - ABYTES / 1024;
      uint32_t o = (uint32_t)q * 1024u + (uint32_t)lane * 16u;
      uint32_t row = o >> 6, colb = o & 63u;
      uint32_t csw = colb ^ ((row & 3u) << 4);
      rowpartB[t2] = row * (NC * 2) + csw;
      loB[t2] = (uint32_t)ABYTES + (uint32_t)q * 1024u;
    }
  }
  const char* baseB = (const char*)dstT + ((size_t)(b * NN + jc * JCHUNK)) * (NC * 2);

  // ---- fragment read offsets (per-lane constants) ----
  uint32_t offA[3], offB[4];
  int jlane[4];
#pragma unroll
  for (int mi = 0; mi < 3; ++mi) {
    int row = wm * 48 + mi * 16 + (lane & 15);
    offA[mi] = (uint32_t)row * (BK * 2) + ((((uint32_t)(lane >> 4)) * 16u) ^ (((uint32_t)row & 3u) << 4));
  }
#pragma unroll
  for (int ni = 0; ni < 4; ++ni) {
    int row = wn * 64 + ni * 16 + (lane & 15);
    offB[ni] = (uint32_t)ABYTES + (uint32_t)row * (BK * 2) + ((((uint32_t)(lane >> 4)) * 16u) ^ (((uint32_t)row & 3u) << 4));
    jlane[ni] = wn * 64 + ni * 16 + (lane & 15);
  }

  floatx4 acc[3][4];
  float asum[3][4], asx[3][4], asy[3][4];
#pragma unroll
  for (int mi = 0; mi < 3; ++mi)
#pragma unroll
    for (int ni = 0; ni < 4; ++ni) acc[mi][ni] = (floatx4){0.f, 0.f, 0.f, 0.f};
#pragma unroll
  for (int mi = 0; mi < 3; ++mi)
#pragma unroll
    for (int r = 0; r < 4; ++r) { asum[mi][r] = 0.f; asx[mi][r] = 0.f; asy[mi][r] = 0.f; }

  auto stage = [&](int s, char* buf) {
    int js = s >> 4, kt = s & 15;
#pragma unroll
    for (int t2 = 0; t2 < 2; ++t2)
      if (t2 < nA) gl_lds16(gA[t2] + kt * (BK * 2), buf + loA[t2]);
#pragma unroll
    for (int t2 = 0; t2 < 2; ++t2)
      if (t2 < nB) gl_lds16(baseB + (size_t)js * (BN * NC * 2) + rowpartB[t2] + kt * (BK * 2), buf + loB[t2]);
  };

  stage(0, lds[0]);
  __syncthreads();

  for (int s = 0; s < NSTEP; ++s) {
    char* cur = lds[s & 1];
    char* nxt = lds[(s + 1) & 1];
    if (s + 1 < NSTEP) stage(s + 1, nxt);

    short8 af[3], bfr[4];
#pragma unroll
    for (int mi = 0; mi < 3; ++mi) af[mi] = *(const short8*)(cur + offA[mi]);
#pragma unroll
    for (int ni = 0; ni < 4; ++ni) bfr[ni] = *(const short8*)(cur + offB[ni]);
#pragma unroll
    for (int mi = 0; mi < 3; ++mi)
#pragma unroll
      for (int ni = 0; ni < 4; ++ni)
        acc[mi][ni] = __builtin_amdgcn_mfma_f32_16x16x32_bf16(af[mi], bfr[ni], acc[mi][ni], 0, 0, 0);

    if ((s & (NKT - 1)) == (NKT - 1)) {
      int js = s >> 4;
      int jcol0 = jc * JCHUNK + js * BN;
#pragma unroll
      for (int ni = 0; ni < 4; ++ni) {
        int j = jcol0 + jlane[ni];
        float cx = (float)(j & 63) + 0.5f;
        float cy = (float)(j >> 6) + 0.5f;
#pragma unroll
        for (int mi = 0; mi < 3; ++mi) {
#pragma unroll
          for (int r = 0; r < 4; ++r) {
            float p = __expf(acc[mi][ni][r]);
            asum[mi][r] += p;
            asx[mi][r] = fmaf(p, cx, asx[mi][r]);
            asy[mi][r] = fmaf(p, cy, asy[mi][r]);
          }
          acc[mi][ni] = (floatx4){0.f, 0.f, 0.f, 0.f};
        }
      }
    }
    __syncthreads();
  }

  // ---- cross-lane reduce (16 lanes sharing the same rows) ----
#pragma unroll
  for (int mi = 0; mi < 3; ++mi)
#pragma unroll
    for (int r = 0; r < 4; ++r) {
#pragma unroll
      for (int m = 1; m < 16; m <<= 1) {
        asum[mi][r] += __shfl_xor(asum[mi][r], m);
        asx[mi][r] += __shfl_xor(asx[mi][r], m);
        asy[mi][r] += __shfl_xor(asy[mi][r], m);
      }
    }
  if ((lane & 15) == 0) {
    int lq = lane >> 4;
#pragma unroll
    for (int mi = 0; mi < 3; ++mi)
#pragma unroll
      for (int r = 0; r < 4; ++r) {
        int row = wm * 48 + mi * 16 + lq * 4 + r;
        int idx = (wn * BM + row) * 3;
        red[idx + 0] = asum[mi][r];
        red[idx + 1] = asx[mi][r];
        red[idx + 2] = asy[mi][r];
      }
  }
  __syncthreads();
  if (tid < BM) {
    float s0 = red[tid * 3 + 0] + red[(BM + tid) * 3 + 0];
    float s1 = red[tid * 3 + 1] + red[(BM + tid) * 3 + 1];
    float s2 = red[tid * 3 + 2] + red[(BM + tid) * 3 + 2];
    size_t o = ((size_t)(b * NP + i0 + tid) * NJC + jc) * 3;
    partials[o + 0] = s0;
    partials[o + 1] = s1;
    partials[o + 2] = s2;
  }
}

// ---------------- K4: finalize ----------------
__global__ void finalize_kernel(const float* __restrict__ partials, float* __restrict__ out) {
  int b = blockIdx.x;
  int t = threadIdx.x;
  float sxt = 0.f, syt = 0.f;
  for (int i = t; i < NP; i += 256) {
    const float* p = partials + ((size_t)(b * NP + i) * NJC) * 3;
    float s = 0.f, sx = 0.f, sy = 0.f;
#pragma unroll
    for (int jc2 = 0; jc2 < NJC; ++jc2) {
      s += p[jc2 * 3 + 0];
      sx += p[jc2 * 3 + 1];
      sy += p[jc2 * 3 + 2];
    }
    sxt += sx / s;
    syt += sy / s;
  }
  __shared__ float rs[256], rs2[256];
  rs[t] = sxt; rs2[t] = syt;
  __syncthreads();
  for (int o = 128; o > 0; o >>= 1) {
    if (t < o) { rs[t] += rs[t + o]; rs2[t] += rs2[t + o]; }
    __syncthreads();
  }
  if (t == 0) {
    float cx = rs[0] / (float)NP, cy = rs2[0] / (float)NP;
    float l = fmaxf(cx - 12.f, 0.f);
    float tp = fmaxf(cy - 12.f, 0.f);
    out[b * 4 + 0] = l;
    out[b * 4 + 1] = tp;
    out[b * 4 + 2] = fminf(l + 24.f, 64.f);
    out[b * 4 + 3] = fminf(tp + 24.f, 64.f);
  }
}

extern "C" void kernel_launch(void* const* d_in, const int* in_sizes, int n_in,
                              void* d_out, int out_size, void* d_ws, size_t ws_size,
                              hipStream_t stream) {
  const float* patch_x = (const float*)d_in[0];
  const float* x = (const float*)d_in[1];
  float* out = (float*)d_out;
  char* ws = (char*)d_ws;

  float* inv_src = (float*)(ws + 0);                         // 73,728 B
  float* inv_dst = (float*)(ws + 73728);                     // 524,288 B
  __hip_bfloat16* srcT = (__hip_bfloat16*)(ws + 598016);     // 18,874,368 B
  __hip_bfloat16* dstT = (__hip_bfloat16*)(ws + 19472384);   // 134,217,728 B
  float* partials = (float*)(ws + 153690112);                // 884,736 B

  norms_kernel<<<dim3((NB * NP + 255) / 256), 256, 0, stream>>>(patch_x, inv_src, NP, NB * NP);
  norms_kernel<<<dim3((NB * NN + 255) / 256), 256, 0, stream>>>(x, inv_dst, NN, NB * NN);
  transpose_kernel<<<dim3(NP / 64, NC / 64, NB), 256, 0, stream>>>(patch_x, inv_src, srcT, NP);
  transpose_kernel<<<dim3(NN / 64, NC / 64, NB), 256, 0, stream>>>(x, inv_dst, dstT, NN);
  affinity_kernel<<<dim3(NP / BM, NJC, NB), 256, 0, stream>>>(srcT, dstT, partials);
  finalize_kernel<<<NB, 256, 0, stream>>>(partials, out);
}

// Round 2
// 250.504 us; speedup vs baseline: 1.9513x; 1.9513x over previous
//
#include <hip/hip_runtime.h>
#include <hip/hip_bf16.h>
#include <stdint.h>

#define NB 32
#define NC 512
#define NP 576
#define NN 4096
#define BN 64
#define BK 32
#define NKT 16
#define BT 8192   // 32 k-rows * 64 j * 4B

typedef __attribute__((ext_vector_type(8))) short short8;
typedef __attribute__((ext_vector_type(4))) float floatx4;

#define AS1 __attribute__((address_space(1)))
#define AS3 __attribute__((address_space(3)))

static __device__ __forceinline__ void gl_lds16(const void* g, void* l) {
  __builtin_amdgcn_global_load_lds((const AS1 uint32_t*)g, (AS3 uint32_t*)l, 16, 0, 0);
}
static __device__ __forceinline__ short f2bf(float f) {
  union { __hip_bfloat16 h; short s; } u;
  u.h = __float2bfloat16(f);
  return u.s;
}

// ---------------- K1: inverse L2 norms over channel dim (patch only) ----------------
__global__ void norms_kernel(const float* __restrict__ in, float* __restrict__ invn,
                             int nsp, int total) {
  int idx = blockIdx.x * 256 + threadIdx.x;
  if (idx >= total) return;
  int b = idx / nsp, sp = idx - b * nsp;
  const float* p = in + (size_t)b * NC * nsp + sp;
  float s = 0.f;
#pragma unroll 8
  for (int c = 0; c < NC; ++c) { float v = p[(size_t)c * nsp]; s = fmaf(v, v, s); }
  invn[idx] = 1.0f / fmaxf(sqrtf(s), 1e-12f);
}

// ---------------- K2: transpose patch [C][P] -> [P][C], scale, bf16 ----------------
__global__ void transpose_kernel(const float* __restrict__ in, const float* __restrict__ invn,
                                 __hip_bfloat16* __restrict__ out, int nsp) {
  __shared__ float tile[64][65];
  int b = blockIdx.z, c0 = blockIdx.y * 64, p0 = blockIdx.x * 64;
  int tx = threadIdx.x & 63, ty = threadIdx.x >> 6;
  const float* src = in + ((size_t)b * NC + c0) * nsp + p0;
#pragma unroll
  for (int r = ty; r < 64; r += 4) tile[r][tx] = src[(size_t)r * nsp + tx];
  __syncthreads();
  __hip_bfloat16* dst = out + ((size_t)b * nsp + p0) * NC + c0;
#pragma unroll
  for (int r = ty; r < 64; r += 4) {
    float iv = invn[b * nsp + p0 + r];
    dst[(size_t)r * NC + tx] = __float2bfloat16(tile[tx][r] * iv);
  }
}

// ---------------- K3: fused GEMM + softmax-reduction (full-M per block) ----------------
// Block: 256 thr (4 waves), each wave owns 144 rows x 64 cols. B (x, fp32) is
// staged to LDS once (read-once from HBM); A (srcT bf16) fragments load
// directly from global (L2-resident per XCD via swizzle). dst norm applied at
// epilogue from in-loop sumsq.
__global__ __launch_bounds__(256, 2)
void affinity_kernel(const __hip_bfloat16* __restrict__ srcT,
                     const float* __restrict__ x,
                     float* __restrict__ partials) {
  const int bid = blockIdx.x;
  const int T = (bid & 7) * 256 + (bid >> 3);   // bijective XCD swizzle (2048 = 8*256)
  const int b = T >> 6, jc = T & 63;
  const int tid = threadIdx.x, lane = tid & 63, w = tid >> 6;
  const int g = lane >> 4, l15 = lane & 15;

  __shared__ __align__(16) char Bl[2][BT];
  __shared__ float red[4][BN];
  __shared__ float invd[BN];

  // ---- staging source (pre-swizzled global so linear LDS dest == swizzled layout) ----
  const char* xbase = (const char*)x + ((size_t)b * NC) * (NN * 4) + (size_t)jc * (BN * 4);
  const char* sg[2]; uint32_t so[2];
#pragma unroll
  for (int q = 0; q < 2; ++q) {
    uint32_t o = (uint32_t)q * 4096u + (uint32_t)tid * 16u;
    uint32_t kk = o >> 8;                               // k-row within tile (256 B rows)
    uint32_t bir = (o & 255u) ^ (((kk >> 3) & 3u) << 6);
    so[q] = o;
    sg[q] = xbase + (size_t)kk * (NN * 4) + bir;
  }

  // ---- A fragment base (direct global loads; row = w*144 + mi*16 + l15) ----
  const char* abase = (const char*)srcT + ((size_t)b * NP + w * 144 + l15) * (NC * 2) + g * 16;

  floatx4 acc[9][4];
#pragma unroll
  for (int mi = 0; mi < 9; ++mi)
#pragma unroll
    for (int ni = 0; ni < 4; ++ni) acc[mi][ni] = (floatx4){0.f, 0.f, 0.f, 0.f};

  float sq = 0.f;
  const int sj = tid & 63, sk = tid >> 6;

#pragma unroll
  for (int q = 0; q < 2; ++q) gl_lds16(sg[q], Bl[0] + so[q]);
  __syncthreads();

  for (int kt = 0; kt < NKT; ++kt) {
    const char* cur = Bl[kt & 1];
    if (kt + 1 < NKT) {
      char* nxt = Bl[(kt + 1) & 1];
#pragma unroll
      for (int q = 0; q < 2; ++q)
        gl_lds16(sg[q] + (size_t)(kt + 1) * (32ull * NN * 4), nxt + so[q]);
    }
    // A fragments: 9 x global dwordx4 (L2-hot)
    short8 af[9];
#pragma unroll
    for (int mi = 0; mi < 9; ++mi)
      af[mi] = *(const short8*)(abase + (size_t)mi * (16 * NC * 2) + kt * (BK * 2));
    // B fragments: transpose-read fp32 from swizzled LDS, convert to bf16
    short8 bfr[4];
#pragma unroll
    for (int ni = 0; ni < 4; ++ni) {
#pragma unroll
      for (int e = 0; e < 8; ++e) {
        float v = *(const float*)(cur + (((uint32_t)(g * 8 + e)) << 8) +
                                  (((uint32_t)(ni ^ g)) << 6) + (uint32_t)l15 * 4u);
        bfr[ni][e] = f2bf(v);
      }
    }
    // per-column sumsq for dst normalization (each (kk,j) touched exactly once)
#pragma unroll
    for (int e = 0; e < 8; ++e) {
      uint32_t kk = (uint32_t)(sk * 8 + e);
      float v = *(const float*)(cur + (kk << 8) + (((uint32_t)(sj * 4)) ^ (((uint32_t)sk & 3u) << 6)));
      sq = fmaf(v, v, sq);
    }
#pragma unroll
    for (int mi = 0; mi < 9; ++mi)
#pragma unroll
      for (int ni = 0; ni < 4; ++ni)
        acc[mi][ni] = __builtin_amdgcn_mfma_f32_16x16x32_bf16(af[mi], bfr[ni], acc[mi][ni], 0, 0, 0);
    __syncthreads();
  }

  // ---- dst inv-norms ----
  red[sk][sj] = sq;
  __syncthreads();
  if (tid < BN) {
    float s = red[0][tid] + red[1][tid] + red[2][tid] + red[3][tid];
    invd[tid] = 1.0f / fmaxf(sqrtf(s), 1e-12f);
  }
  __syncthreads();

  float iv[4], cxj[4];
#pragma unroll
  for (int ni = 0; ni < 4; ++ni) {
    iv[ni] = invd[ni * 16 + l15];
    cxj[ni] = (float)(ni * 16 + l15) + 0.5f;    // cx = (j & 63) + 0.5, j = jc*64 + jloc
  }

  // ---- exp + weighted-coordinate reduction (cy = jc + 0.5 is block-uniform) ----
#pragma unroll
  for (int mi = 0; mi < 9; ++mi) {
    float s[4] = {0.f, 0.f, 0.f, 0.f}, sx[4] = {0.f, 0.f, 0.f, 0.f};
#pragma unroll
    for (int ni = 0; ni < 4; ++ni)
#pragma unroll
      for (int r = 0; r < 4; ++r) {
        float p = __expf(acc[mi][ni][r] * iv[ni]);
        s[r] += p;
        sx[r] = fmaf(p, cxj[ni], sx[r]);
      }
#pragma unroll
    for (int r = 0; r < 4; ++r) {
#pragma unroll
      for (int m = 1; m < 16; m <<= 1) {
        s[r] += __shfl_xor(s[r], m);
        sx[r] += __shfl_xor(sx[r], m);
      }
    }
    if (l15 == 0) {
#pragma unroll
      for (int r = 0; r < 4; ++r) {
        int row = w * 144 + mi * 16 + g * 4 + r;
        float* o = partials + ((size_t)(b * NP + row) * 64 + jc) * 2;
        o[0] = s[r];
        o[1] = sx[r];
      }
    }
  }
}

// ---------------- K4: finalize ----------------
__global__ void finalize_kernel(const float* __restrict__ partials, float* __restrict__ out) {
  int b = blockIdx.x;
  int t = threadIdx.x;
  float sxt = 0.f, syt = 0.f;
  for (int i = t; i < NP; i += 256) {
    const float* p = partials + ((size_t)(b * NP + i) * 64) * 2;
    float s = 0.f, sx = 0.f, sy = 0.f;
#pragma unroll
    for (int jc2 = 0; jc2 < 64; ++jc2) {
      float ss = p[jc2 * 2];
      s += ss;
      sx += p[jc2 * 2 + 1];
      sy = fmaf(ss, (float)jc2 + 0.5f, sy);
    }
    sxt += sx / s;
    syt += sy / s;
  }
  __shared__ float rs[256], rs2[256];
  rs[t] = sxt; rs2[t] = syt;
  __syncthreads();
  for (int o = 128; o > 0; o >>= 1) {
    if (t < o) { rs[t] += rs[t + o]; rs2[t] += rs2[t + o]; }
    __syncthreads();
  }
  if (t == 0) {
    float cx = rs[0] / (float)NP, cy = rs2[0] / (float)NP;
    float l = fmaxf(cx - 12.f, 0.f);
    float tp = fmaxf(cy - 12.f, 0.f);
    out[b * 4 + 0] = l;
    out[b * 4 + 1] = tp;
    out[b * 4 + 2] = fminf(l + 24.f, 64.f);
    out[b * 4 + 3] = fminf(tp + 24.f, 64.f);
  }
}

extern "C" void kernel_launch(void* const* d_in, const int* in_sizes, int n_in,
                              void* d_out, int out_size, void* d_ws, size_t ws_size,
                              hipStream_t stream) {
  const float* patch_x = (const float*)d_in[0];
  const float* x = (const float*)d_in[1];
  float* out = (float*)d_out;
  char* ws = (char*)d_ws;

  float* inv_src = (float*)(ws + 0);                       //    73,728 B
  __hip_bfloat16* srcT = (__hip_bfloat16*)(ws + 73728);    // 18,874,368 B
  float* partials = (float*)(ws + 18948096);               //  9,437,184 B  (total ~28.4 MB)

  norms_kernel<<<dim3((NB * NP + 255) / 256), 256, 0, stream>>>(patch_x, inv_src, NP, NB * NP);
  transpose_kernel<<<dim3(NP / 64, NC / 64, NB), 256, 0, stream>>>(patch_x, inv_src, srcT, NP);
  affinity_kernel<<<dim3(NB * BN), 256, 0, stream>>>(srcT, x, partials);
  finalize_kernel<<<NB, 256, 0, stream>>>(partials, out);
}

// Round 3
// 238.813 us; speedup vs baseline: 2.0469x; 1.0490x over previous
//
#include <hip/hip_runtime.h>
#include <hip/hip_bf16.h>
#include <stdint.h>

#define NB 32
#define NC 512
#define NP 576
#define NN 4096

typedef __attribute__((ext_vector_type(8))) short short8;
typedef __attribute__((ext_vector_type(4))) float floatx4;

static __device__ __forceinline__ short f2bf(float f) {
  union { __hip_bfloat16 h; short s; } u;
  u.h = __float2bfloat16(f);
  return u.s;
}

#define GLOAD_F32(dst, voff, sbase) \
  asm volatile("global_load_dword %0, %1, %2" : "=v"(dst) : "v"(voff), "s"(sbase))
#define GLOAD_B128(dst, voff, sbase) \
  asm volatile("global_load_dwordx4 %0, %1, %2" : "=v"(dst) : "v"(voff), "s"(sbase))
#define DSWRITE_B128(addr, data) \
  asm volatile("ds_write_b128 %0, %1" :: "v"(addr), "v"(data))
#define WAIT_VMCNT(N) asm volatile("s_waitcnt vmcnt(" #N ")" ::: "memory")
#define WAIT_LGKM0    asm volatile("s_waitcnt lgkmcnt(0)" ::: "memory")
#define SBAR() do { asm volatile("" ::: "memory"); __builtin_amdgcn_s_barrier(); asm volatile("" ::: "memory"); } while (0)
#define SCHEDBAR() __builtin_amdgcn_sched_barrier(0)

// ---------------- K1: inverse L2 norms over channel dim (patch only) ----------------
__global__ void norms_kernel(const float* __restrict__ in, float* __restrict__ invn,
                             int nsp, int total) {
  int idx = blockIdx.x * 256 + threadIdx.x;
  if (idx >= total) return;
  int b = idx / nsp, sp = idx - b * nsp;
  const float* p = in + (size_t)b * NC * nsp + sp;
  float s = 0.f;
#pragma unroll 8
  for (int c = 0; c < NC; ++c) { float v = p[(size_t)c * nsp]; s = fmaf(v, v, s); }
  invn[idx] = 1.0f / fmaxf(sqrtf(s), 1e-12f);
}

// ---------------- K2: transpose patch [C][P] -> [P][C], scale, bf16 ----------------
__global__ void transpose_kernel(const float* __restrict__ in, const float* __restrict__ invn,
                                 __hip_bfloat16* __restrict__ out, int nsp) {
  __shared__ float tile[64][65];
  int b = blockIdx.z, c0 = blockIdx.y * 64, p0 = blockIdx.x * 64;
  int tx = threadIdx.x & 63, ty = threadIdx.x >> 6;
  const float* src = in + ((size_t)b * NC + c0) * nsp + p0;
#pragma unroll
  for (int r = ty; r < 64; r += 4) tile[r][tx] = src[(size_t)r * nsp + tx];
  __syncthreads();
  __hip_bfloat16* dst = out + ((size_t)b * nsp + p0) * NC + c0;
#pragma unroll
  for (int r = ty; r < 64; r += 4) {
    float iv = invn[b * nsp + p0 + r];
    dst[(size_t)r * NC + tx] = __float2bfloat16(tile[tx][r] * iv);
  }
}

// ---------------- K3: fused GEMM + softmax-reduction ----------------
// Per block: full M (576 rows) x 64 j-cols, K=512 in 16 steps of 32.
// B staged by reg-transpose: wave w loads k-rows w*8..w*8+7 (fp32, coalesced),
// converts, one ds_write_b128/lane into [g][j][16B] k-major layout.
// All VMEM inline-asm, counted vmcnt(8), raw barriers (no vmcnt(0) in loop).
__global__ __launch_bounds__(256, 2)
void affinity_kernel(const __hip_bfloat16* __restrict__ srcT,
                     const float* __restrict__ x,
                     float* __restrict__ partials) {
  const int bid = blockIdx.x;
  const int T = (bid & 7) * 256 + (bid >> 3);   // bijective XCD swizzle (2048 = 8*256)
  const int b = T >> 6, jc = T & 63;
  const int tid = threadIdx.x, lane = tid & 63, w = tid >> 6;
  const int g = lane >> 4, l15 = lane & 15;

  __shared__ __align__(16) char Bl[2][4096];
  __shared__ float red[4][64];
  __shared__ float invd[64];

  const uint64_t sA = (uint64_t)(uintptr_t)srcT;
  const uint64_t sX = (uint64_t)(uintptr_t)x;

  // A voffsets (bytes): row = w*144 + mi*16 + l15, col-bytes g*16 (+kt*64)
  uint32_t voffA[9];
#pragma unroll
  for (int mi = 0; mi < 9; ++mi)
    voffA[mi] = (uint32_t)(b * NP + w * 144 + mi * 16 + l15) * (uint32_t)(NC * 2)
              + (uint32_t)g * 16u;

  // G voffsets (bytes): k-row = w*8 + r (+kt*32), j = jc*64 + lane
  uint32_t voffG[8];
#pragma unroll
  for (int r = 0; r < 8; ++r)
    voffG[r] = (uint32_t)(b * NC + w * 8 + r) * (uint32_t)(NN * 4)
             + (uint32_t)(jc * 64 + lane) * 4u;

  // LDS addresses
  const uint32_t ldsbase = (uint32_t)(uintptr_t)(&Bl[0][0]);
  const uint32_t wraddr = ldsbase + (uint32_t)w * 1024u + (uint32_t)lane * 16u;

  floatx4 acc[9][4];
#pragma unroll
  for (int mi = 0; mi < 9; ++mi)
#pragma unroll
    for (int ni = 0; ni < 4; ++ni) acc[mi][ni] = (floatx4){0.f, 0.f, 0.f, 0.f};

  short8 af[9];
  float GA[8], GB[8];
  float sq = 0.f;

  auto issueA = [&](int kt) {
#pragma unroll
    for (int mi = 0; mi < 9; ++mi) {
      uint32_t v = voffA[mi] + (uint32_t)kt * 64u;
      GLOAD_B128(af[mi], v, sA);
    }
  };
  auto issueG = [&](int kt, float (&Gv)[8]) {
#pragma unroll
    for (int r = 0; r < 8; ++r) {
      uint32_t v = voffG[r] + (uint32_t)kt * (32u * NN * 4u);
      GLOAD_F32(Gv[r], v, sX);
    }
  };
  auto cvtWrite = [&](float (&Gv)[8], uint32_t slotoff) {
    short8 bf;
#pragma unroll
    for (int r = 0; r < 8; ++r) {
      sq = fmaf(Gv[r], Gv[r], sq);
      bf[r] = f2bf(Gv[r]);
    }
    DSWRITE_B128(wraddr + slotoff, bf);
  };
  auto mfmaStep = [&](uint32_t slotoff) {
#pragma unroll
    for (int ni = 0; ni < 4; ++ni) {
      short8 bfr = *(const short8*)(&Bl[0][0] + slotoff + (uint32_t)g * 1024u
                                    + (uint32_t)ni * 256u + (uint32_t)l15 * 16u);
#pragma unroll
      for (int mi = 0; mi < 9; ++mi)
        acc[mi][ni] = __builtin_amdgcn_mfma_f32_16x16x32_bf16(af[mi], bfr, acc[mi][ni], 0, 0, 0);
    }
  };

  // ---- prologue: G0 -> GA, G1 -> GB; write buf0 ----
  issueG(0, GA);
  issueG(1, GB);
  WAIT_VMCNT(8); SCHEDBAR();      // GA done, GB in flight
  cvtWrite(GA, 0);
  WAIT_LGKM0;
  SBAR();

  // ---- main loop: iters 0..13 (double-stepped) ----
#pragma unroll 1
  for (int kt = 0; kt < 14; kt += 2) {
    // even half: consume tile kt (buf0), write tile kt+1 (buf1)
    issueA(kt);
    issueG(kt + 2, GA);
    WAIT_VMCNT(8); SCHEDBAR();    // drains G[kt+1](GB) + A; G[kt+2] in flight
    cvtWrite(GB, 4096u);
    mfmaStep(0u);
    WAIT_LGKM0;
    SBAR();
    // odd half: consume tile kt+1 (buf1), write tile kt+2 (buf0)
    issueA(kt + 1);
    issueG(kt + 3, GB);
    WAIT_VMCNT(8); SCHEDBAR();    // drains G[kt+2](GA) + A; G[kt+3] in flight
    cvtWrite(GA, 0u);
    mfmaStep(4096u);
    WAIT_LGKM0;
    SBAR();
  }
  // ---- tail: iter 14 ----
  issueA(14);
  WAIT_VMCNT(0); SCHEDBAR();      // drains G15(GB) + A
  cvtWrite(GB, 4096u);
  mfmaStep(0u);
  WAIT_LGKM0;
  SBAR();
  // ---- tail: iter 15 ----
  issueA(15);
  WAIT_VMCNT(0); SCHEDBAR();
  mfmaStep(4096u);

  // ---- dst inv-norms from in-loop fp32 sumsq (lane's column j = lane) ----
  __syncthreads();
  red[w][lane] = sq;
  __syncthreads();
  if (tid < 64)
    invd[tid] = rsqrtf(fmaxf(red[0][tid] + red[1][tid] + red[2][tid] + red[3][tid], 1e-24f));
  __syncthreads();

  float iv[4], cxj[4];
#pragma unroll
  for (int ni = 0; ni < 4; ++ni) {
    iv[ni] = invd[ni * 16 + l15];
    cxj[ni] = (float)(ni * 16 + l15) + 0.5f;   // cx = (j & 63) + 0.5
  }

  // ---- exp + weighted reduction (cy = jc + 0.5 block-uniform) ----
#pragma unroll
  for (int mi = 0; mi < 9; ++mi) {
    float s[4] = {0.f, 0.f, 0.f, 0.f}, sx[4] = {0.f, 0.f, 0.f, 0.f};
#pragma unroll
    for (int ni = 0; ni < 4; ++ni)
#pragma unroll
      for (int r = 0; r < 4; ++r) {
        float p = __expf(acc[mi][ni][r] * iv[ni]);
        s[r] += p;
        sx[r] = fmaf(p, cxj[ni], sx[r]);
      }
#pragma unroll
    for (int r = 0; r < 4; ++r) {
#pragma unroll
      for (int m = 1; m < 16; m <<= 1) {
        s[r] += __shfl_xor(s[r], m);
        sx[r] += __shfl_xor(sx[r], m);
      }
    }
    if (l15 == 0) {
#pragma unroll
      for (int r = 0; r < 4; ++r) {
        int row = w * 144 + mi * 16 + g * 4 + r;
        float* o = partials + ((size_t)(b * NP + row) * 64 + jc) * 2;
        o[0] = s[r];
        o[1] = sx[r];
      }
    }
  }
}

// ---------------- K4: finalize ----------------
__global__ void finalize_kernel(const float* __restrict__ partials, float* __restrict__ out) {
  int b = blockIdx.x;
  int t = threadIdx.x;
  float sxt = 0.f, syt = 0.f;
  for (int i = t; i < NP; i += 256) {
    const float* p = partials + ((size_t)(b * NP + i) * 64) * 2;
    float s = 0.f, sx = 0.f, sy = 0.f;
#pragma unroll
    for (int jc2 = 0; jc2 < 64; ++jc2) {
      float ss = p[jc2 * 2];
      s += ss;
      sx += p[jc2 * 2 + 1];
      sy = fmaf(ss, (float)jc2 + 0.5f, sy);
    }
    sxt += sx / s;
    syt += sy / s;
  }
  __shared__ float rs[256], rs2[256];
  rs[t] = sxt; rs2[t] = syt;
  __syncthreads();
  for (int o = 128; o > 0; o >>= 1) {
    if (t < o) { rs[t] += rs[t + o]; rs2[t] += rs2[t + o]; }
    __syncthreads();
  }
  if (t == 0) {
    float cx = rs[0] / (float)NP, cy = rs2[0] / (float)NP;
    float l = fmaxf(cx - 12.f, 0.f);
    float tp = fmaxf(cy - 12.f, 0.f);
    out[b * 4 + 0] = l;
    out[b * 4 + 1] = tp;
    out[b * 4 + 2] = fminf(l + 24.f, 64.f);
    out[b * 4 + 3] = fminf(tp + 24.f, 64.f);
  }
}

extern "C" void kernel_launch(void* const* d_in, const int* in_sizes, int n_in,
                              void* d_out, int out_size, void* d_ws, size_t ws_size,
                              hipStream_t stream) {
  const float* patch_x = (const float*)d_in[0];
  const float* x = (const float*)d_in[1];
  float* out = (float*)d_out;
  char* ws = (char*)d_ws;

  float* inv_src = (float*)(ws + 0);                       //    73,728 B
  __hip_bfloat16* srcT = (__hip_bfloat16*)(ws + 73728);    // 18,874,368 B
  float* partials = (float*)(ws + 18948096);               //  9,437,184 B

  norms_kernel<<<dim3((NB * NP + 255) / 256), 256, 0, stream>>>(patch_x, inv_src, NP, NB * NP);
  transpose_kernel<<<dim3(NP / 64, NC / 64, NB), 256, 0, stream>>>(patch_x, inv_src, srcT, NP);
  affinity_kernel<<<dim3(NB * 64), 256, 0, stream>>>(srcT, x, partials);
  finalize_kernel<<<NB, 256, 0, stream>>>(partials, out);
}